// Round 4
// baseline (132.293 us; speedup 1.0000x reference)
//
#include <hip/hip_runtime.h>
#include <hip/hip_bf16.h>

typedef unsigned short u16;
typedef __attribute__((ext_vector_type(8))) short bf16x8;
typedef __attribute__((ext_vector_type(4))) float f32x4;

typedef const __attribute__((address_space(1))) void gvoid_t;
typedef __attribute__((address_space(3))) void lvoid_t;

__device__ __forceinline__ void gload_lds16(const void* g, void* l) {
  __builtin_amdgcn_global_load_lds((gvoid_t*)g, (lvoid_t*)l, 16, 0, 0);
}

__device__ __forceinline__ u16 f2bf(float f) {
  union { float f; unsigned u; } a;
  a.f = f;
  unsigned r = (a.u + 0x7FFFu + ((a.u >> 16) & 1u)) >> 16;  // RN-even
  return (u16)r;
}

// ---------------------------------------------------------------------------
// Prep: fp32 -> bf16 copies of x and y, plus per-row sum of squares.
// ---------------------------------------------------------------------------
__global__ __launch_bounds__(128) void rbf_prep(
    const float* __restrict__ x, const float* __restrict__ y,
    u16* __restrict__ xb, u16* __restrict__ yb,
    float* __restrict__ xsq, float* __restrict__ ysq,
    int N, int M, int D) {
  int row = blockIdx.x;
  const float* src;
  u16* dst;
  float* sq;
  if (row < N) {
    src = x + (size_t)row * D;
    dst = xb + (size_t)row * D;
    sq = xsq + row;
  } else {
    int r = row - N;
    src = y + (size_t)r * D;
    dst = yb + (size_t)r * D;
    sq = ysq + r;
  }
  int t = threadIdx.x;
  float4 v = reinterpret_cast<const float4*>(src)[t];
  float s = v.x * v.x + v.y * v.y + v.z * v.z + v.w * v.w;
  ushort4 o;
  o.x = f2bf(v.x);
  o.y = f2bf(v.y);
  o.z = f2bf(v.z);
  o.w = f2bf(v.w);
  reinterpret_cast<ushort4*>(dst)[t] = o;
  #pragma unroll
  for (int off = 32; off > 0; off >>= 1) s += __shfl_down(s, off, 64);
  __shared__ float red[2];
  if ((t & 63) == 0) red[t >> 6] = s;
  __syncthreads();
  if (t == 0) sq[0] = red[0] + red[1];
}

// ---------------------------------------------------------------------------
// 256x256 deep-pipelined GEMM + RBF epilogue.
//   8 waves (2Mx4N), BK=64, LDS [2 buf][A,B][256x64] bf16 = 128 KiB.
//   T2 swizzle (3-bit): phys chunk = logical chunk ^ (row&7); staging source
//   inverse-swizzled, LDS dest linear, ds_read applies same XOR.
//   MFMA operands SWAPPED: mfma(y_frag, x_frag) -> D row = j, col = i ->
//   per-thread regs are 4 consecutive output columns -> float4 stores.
//   NEW (R4): 2D supertile block->XCD mapping. 32x32 tile grid, XCDs in 4x2
//   regions of 8x16 tiles, column-major (8-row cols) within a region ->
//   ~32 resident blocks/XCD touch 8 A-panels + ~5 B-panels = 3.25 MB <= L2.
//   L3 panel traffic drops 512 MB -> ~48 MB.
// ---------------------------------------------------------------------------
#define BM 256
#define BN 256
#define BK 64

__global__ __launch_bounds__(512, 2) void rbf_gemm(
    const u16* __restrict__ xb, const u16* __restrict__ yb,
    const float* __restrict__ xsq, const float* __restrict__ ysq,
    const float* __restrict__ gptr, float* __restrict__ out,
    int N, int M, int D) {
  __shared__ u16 lds[2][2][BM * BK];  // 128 KiB

  int bid = blockIdx.x;
  int nbr = N / BM, nbc = M / BN;
  int trow, tcol;
  if (nbr == 32 && nbc == 32) {
    // supertile: XCD (bid&7) owns an 8x16-tile region; column-major inside.
    int xcd = bid & 7;
    int s = bid >> 3;  // 0..127
    trow = ((xcd >> 1) << 3) + (s & 7);
    tcol = ((xcd & 1) << 4) + (s >> 3);
  } else {
    int cpx = gridDim.x >> 3;
    int swz = (bid & 7) * cpx + (bid >> 3);
    trow = swz / nbc;
    tcol = swz % nbc;
  }
  int brow = trow * BM;
  int bcol = tcol * BN;

  int tid = threadIdx.x;
  int w = tid >> 6;    // wave 0..7
  int lane = tid & 63;
  int wm = w >> 2;     // 0..1 : row half (128 rows)
  int wn = w & 3;      // 0..3 : col quarter (64 cols)
  int fr = lane & 15;
  int fq = lane >> 4;

  // --- staging: wave w stages rows w*32..w*32+31; each load = 8 rows x 128B.
  int srow = lane >> 3;                                   // 0..7
  int scol = ((lane & 7) ^ (srow & 7)) * 8;               // elems
  const u16* xsrc = xb + (size_t)(brow + w * 32 + srow) * D + scol;
  const u16* ysrc = yb + (size_t)(bcol + w * 32 + srow) * D + scol;
  int sdst = w * 2048;  // w*32 rows * 64 elems

  // --- fragment read offsets: col = (kk*32 + fq*8) ^ ((fr&7)*8) elems ---
  int cxor = (fr & 7) * 8;
  int colx0 = (fq * 8) ^ cxor;         // kk = 0
  int colx1 = (32 + fq * 8) ^ cxor;    // kk = 1
  int aoff0 = (wm * 128 + fr) * 64 + colx0;
  int aoff1 = (wm * 128 + fr) * 64 + colx1;
  int boff0 = (wn * 64 + fr) * 64 + colx0;
  int boff1 = (wn * 64 + fr) * 64 + colx1;

  f32x4 acc[8][4];
  #pragma unroll
  for (int m = 0; m < 8; ++m)
    #pragma unroll
    for (int n = 0; n < 4; ++n)
      acc[m][n] = (f32x4){0.f, 0.f, 0.f, 0.f};

  auto stage = [&](int kt, int b) {
    const u16* xs = xsrc + kt * 64;
    const u16* ys = ysrc + kt * 64;
    u16* la = &lds[b][0][sdst];
    u16* lb = &lds[b][1][sdst];
    #pragma unroll
    for (int i = 0; i < 4; ++i)
      gload_lds16(xs + (size_t)i * 8 * D, la + i * 512);
    #pragma unroll
    for (int i = 0; i < 4; ++i)
      gload_lds16(ys + (size_t)i * 8 * D, lb + i * 512);
  };

  // Swapped operands: D[j][i], j = fq*4 + r, i = fr.
#define PHASE(MH, NH, RA, RB)                                                  \
  {                                                                            \
    if (RA) {                                                                  \
      _Pragma("unroll") for (int mi = 0; mi < 4; ++mi) {                       \
        af[mi][0] = *(const bf16x8*)&A[aoff0 + (MH * 4 + mi) * 1024];          \
        af[mi][1] = *(const bf16x8*)&A[aoff1 + (MH * 4 + mi) * 1024];          \
      }                                                                        \
    }                                                                          \
    if (RB) {                                                                  \
      _Pragma("unroll") for (int ni = 0; ni < 2; ++ni) {                       \
        bf[ni][0] = *(const bf16x8*)&B[boff0 + (NH * 2 + ni) * 1024];          \
        bf[ni][1] = *(const bf16x8*)&B[boff1 + (NH * 2 + ni) * 1024];          \
      }                                                                        \
    }                                                                          \
    __builtin_amdgcn_s_setprio(1);                                             \
    _Pragma("unroll") for (int mi = 0; mi < 4; ++mi)                           \
      _Pragma("unroll") for (int ni = 0; ni < 2; ++ni) {                       \
        acc[MH * 4 + mi][NH * 2 + ni] =                                        \
            __builtin_amdgcn_mfma_f32_16x16x32_bf16(                           \
                bf[ni][0], af[mi][0], acc[MH * 4 + mi][NH * 2 + ni], 0, 0, 0); \
        acc[MH * 4 + mi][NH * 2 + ni] =                                        \
            __builtin_amdgcn_mfma_f32_16x16x32_bf16(                           \
                bf[ni][1], af[mi][1], acc[MH * 4 + mi][NH * 2 + ni], 0, 0, 0); \
      }                                                                        \
    __builtin_amdgcn_s_setprio(0);                                             \
  }

  int nkt = D >> 6;  // 8
  stage(0, 0);
  stage(1, 1);
  for (int t = 0; t < nkt; ++t) {
    int b = t & 1;
    // counted wait: force kt's 8 loads; keep kt+1's 8 in flight
    if (t + 1 < nkt)
      asm volatile("s_waitcnt vmcnt(8)" ::: "memory");
    else
      asm volatile("s_waitcnt vmcnt(0)" ::: "memory");
    __builtin_amdgcn_sched_barrier(0);
    __builtin_amdgcn_s_barrier();  // staged data visible to all waves
    __builtin_amdgcn_sched_barrier(0);

    const u16* A = &lds[b][0][0];
    const u16* B = &lds[b][1][0];
    bf16x8 af[4][2], bf[2][2];

    PHASE(0, 0, true, true);
    __builtin_amdgcn_s_barrier();
    PHASE(0, 1, false, true);
    __builtin_amdgcn_s_barrier();
    PHASE(1, 1, true, false);
    __builtin_amdgcn_s_barrier();
    PHASE(1, 0, false, true);

    // all my ds_reads of buf b retired before anyone re-stages into it
    asm volatile("s_waitcnt lgkmcnt(0)" ::: "memory");
    __builtin_amdgcn_sched_barrier(0);
    __builtin_amdgcn_s_barrier();
    __builtin_amdgcn_sched_barrier(0);
    if (t + 2 < nkt) stage(t + 2, b);
  }
#undef PHASE

  // Epilogue: d2 = |x|^2 + |y|^2 - 2 x.y ; out = exp(-gamma*d2)
  float gamma = gptr[0];
  #pragma unroll
  for (int m = 0; m < 8; ++m) {
    int i = brow + wm * 128 + m * 16 + fr;
    float xs = xsq[i];
    size_t ro = (size_t)i * M;
    #pragma unroll
    for (int n = 0; n < 4; ++n) {
      int jb = bcol + wn * 64 + n * 16 + fq * 4;
      float4 ys4 = *reinterpret_cast<const float4*>(&ysq[jb]);
      float4 e;
      e.x = __expf(-gamma * fmaxf(xs + ys4.x - 2.0f * acc[m][n][0], 0.0f));
      e.y = __expf(-gamma * fmaxf(xs + ys4.y - 2.0f * acc[m][n][1], 0.0f));
      e.z = __expf(-gamma * fmaxf(xs + ys4.z - 2.0f * acc[m][n][2], 0.0f));
      e.w = __expf(-gamma * fmaxf(xs + ys4.w - 2.0f * acc[m][n][3], 0.0f));
      *reinterpret_cast<float4*>(&out[ro + jb]) = e;
    }
  }
}

// ---------------------------------------------------------------------------
// Fallback: fp32 LDS-tiled, slow but correct for odd shapes.
// ---------------------------------------------------------------------------
__global__ __launch_bounds__(256) void rbf_naive(
    const float* __restrict__ x, const float* __restrict__ y,
    const float* __restrict__ gptr, float* __restrict__ out,
    int N, int M, int D) {
  __shared__ float xs[16][17];
  __shared__ float ys[16][17];
  int nbn = M / 16;
  int brow = (blockIdx.x / nbn) * 16;
  int bcol = (blockIdx.x % nbn) * 16;
  int ti = threadIdx.x >> 4, tj = threadIdx.x & 15;
  float dacc = 0.f, xacc = 0.f, yacc = 0.f;
  for (int k0 = 0; k0 < D; k0 += 16) {
    xs[ti][tj] = x[(size_t)(brow + ti) * D + k0 + tj];
    ys[ti][tj] = y[(size_t)(bcol + ti) * D + k0 + tj];
    __syncthreads();
    #pragma unroll
    for (int kk = 0; kk < 16; ++kk) {
      float xv = xs[ti][kk], yv = ys[tj][kk];
      dacc += xv * yv;
      xacc += xv * xv;
      yacc += yv * yv;
    }
    __syncthreads();
  }
  float gamma = gptr[0];
  float d2 = fmaxf(xacc + yacc - 2.f * dacc, 0.f);
  out[(size_t)(brow + ti) * M + (bcol + tj)] = __expf(-gamma * d2);
}

// ---------------------------------------------------------------------------
extern "C" void kernel_launch(void* const* d_in, const int* in_sizes, int n_in,
                              void* d_out, int out_size, void* d_ws,
                              size_t ws_size, hipStream_t stream) {
  const float* x = (const float*)d_in[0];
  const float* y = (const float*)d_in[1];
  const float* g = (const float*)d_in[2];
  float* out = (float*)d_out;

  const int D = 512;
  const int N = in_sizes[0] / D;
  const int M = in_sizes[1] / D;

  size_t need = (size_t)(N + M) * D * sizeof(u16) + (size_t)(N + M) * sizeof(float);
  bool shapes_ok = (N % BM == 0) && (M % BN == 0) && (D % BK == 0) && (D / BK >= 2);

  if (ws_size >= need && shapes_ok) {
    u16* xb = (u16*)d_ws;
    u16* yb = xb + (size_t)N * D;
    float* xsq = (float*)(yb + (size_t)M * D);
    float* ysq = xsq + N;

    rbf_prep<<<N + M, 128, 0, stream>>>(x, y, xb, yb, xsq, ysq, N, M, D);
    int nwg = (N / BM) * (M / BN);
    rbf_gemm<<<nwg, 512, 0, stream>>>(xb, yb, xsq, ysq, g, out, N, M, D);
  } else {
    rbf_naive<<<(N / 16) * (M / 16), 256, 0, stream>>>(x, y, g, out, N, M, D);
  }
}

// Round 5
// 112.734 us; speedup vs baseline: 1.1735x; 1.1735x over previous
//
#include <hip/hip_runtime.h>
#include <hip/hip_bf16.h>

typedef unsigned short u16;
typedef __attribute__((ext_vector_type(8))) short bf16x8;
typedef __attribute__((ext_vector_type(4))) float f32x4;

typedef const __attribute__((address_space(1))) void gvoid_t;
typedef __attribute__((address_space(3))) void lvoid_t;

__device__ __forceinline__ void gload_lds16(const void* g, void* l) {
  __builtin_amdgcn_global_load_lds((gvoid_t*)g, (lvoid_t*)l, 16, 0, 0);
}

__device__ __forceinline__ u16 f2bf(float f) {
  union { float f; unsigned u; } a;
  a.f = f;
  unsigned r = (a.u + 0x7FFFu + ((a.u >> 16) & 1u)) >> 16;  // RN-even
  return (u16)r;
}

// ---------------------------------------------------------------------------
// Prep: fp32 -> bf16 copies of x and y, plus per-row sum of squares.
// ---------------------------------------------------------------------------
__global__ __launch_bounds__(128) void rbf_prep(
    const float* __restrict__ x, const float* __restrict__ y,
    u16* __restrict__ xb, u16* __restrict__ yb,
    float* __restrict__ xsq, float* __restrict__ ysq,
    int N, int M, int D) {
  int row = blockIdx.x;
  const float* src;
  u16* dst;
  float* sq;
  if (row < N) {
    src = x + (size_t)row * D;
    dst = xb + (size_t)row * D;
    sq = xsq + row;
  } else {
    int r = row - N;
    src = y + (size_t)r * D;
    dst = yb + (size_t)r * D;
    sq = ysq + r;
  }
  int t = threadIdx.x;
  float4 v = reinterpret_cast<const float4*>(src)[t];
  float s = v.x * v.x + v.y * v.y + v.z * v.z + v.w * v.w;
  ushort4 o;
  o.x = f2bf(v.x);
  o.y = f2bf(v.y);
  o.z = f2bf(v.z);
  o.w = f2bf(v.w);
  reinterpret_cast<ushort4*>(dst)[t] = o;
  #pragma unroll
  for (int off = 32; off > 0; off >>= 1) s += __shfl_down(s, off, 64);
  __shared__ float red[2];
  if ((t & 63) == 0) red[t >> 6] = s;
  __syncthreads();
  if (t == 0) sq[0] = red[0] + red[1];
}

// ---------------------------------------------------------------------------
// 128x128 tile, BK=64, 4 waves (2Mx2N), LDS 64 KiB double-buffer ->
// 2 INDEPENDENT blocks/CU (the structural change: cross-block overlap of
// epilogue/stores/stage-latency with K-loop compute).
// 2 barriers per K-tile only; all frags read once (af[4][2], bf[4][2]);
// compiler interleaves ds_read/MFMA via progressive lgkmcnt.
// T2 swizzle: chunk ^= row&7 both sides (involution; verified R2/R3).
// Swapped MFMA operands: D[j][i] -> float4 output stores.
// Column-band supertile: XCD x owns tile-cols 8x..8x+7; walks 8x8 regions.
// exp2-fused epilogue: gamma*log2e folded into norms.
// ---------------------------------------------------------------------------
#define BM 128
#define BN 128
#define BK 64

__global__ __launch_bounds__(256, 2) void rbf_gemm(
    const u16* __restrict__ xb, const u16* __restrict__ yb,
    const float* __restrict__ xsq, const float* __restrict__ ysq,
    const float* __restrict__ gptr, float* __restrict__ out,
    int N, int M, int D) {
  __shared__ u16 lds[2][2][BM * BK];  // 64 KiB

  int bid = blockIdx.x;
  int nbr = N / BM, nbc = M / BN;
  int trow, tcol;
  if (nbr == 64 && nbc == 64) {
    // XCD x owns tile-columns x*8..x*8+7, walked in 8x8-tile regions
    // (column-major inside a region). Resident set/XCD = 64 blocks = one
    // region: A 1 MB + B 1 MB in L2; B-panels never change for an XCD.
    int xcd = bid & 7;
    int s = bid >> 3;        // 0..511
    int gr = s >> 6;         // region row 0..7
    int q = s & 63;          // within-region, column-major
    trow = gr * 8 + (q & 7);
    tcol = xcd * 8 + (q >> 3);
  } else {
    int cpx = gridDim.x >> 3;
    int swz = (bid & 7) * cpx + (bid >> 3);
    trow = swz / nbc;
    tcol = swz % nbc;
  }
  int brow = trow * BM;
  int bcol = tcol * BN;

  int tid = threadIdx.x;
  int w = tid >> 6;       // wave 0..3
  int lane = tid & 63;
  int wm = w >> 1;        // 0..1 row half (64 rows)
  int wn = w & 1;         // 0..1 col half (64 cols)
  int fr = lane & 15;
  int fq = lane >> 4;

  // --- staging: wave w stages rows w*32..w*32+31 of A and B tiles ---
  int srow = lane >> 3;                        // 0..7
  int scol = ((lane & 7) ^ srow) * 8;          // inverse-swizzled source col
  const u16* xsrc = xb + (size_t)(brow + w * 32 + srow) * D + scol;
  const u16* ysrc = yb + (size_t)(bcol + w * 32 + srow) * D + scol;
  int sdst = w * 2048;  // 32 rows * 64 elems

  // --- fragment read offsets: chunk ^= (row&7) ---
  int cxor = (fr & 7) * 8;
  int colx0 = (fq * 8) ^ cxor;        // kk=0, logical chunks 0..3
  int colx1 = (32 + fq * 8) ^ cxor;   // kk=1, logical chunks 4..7
  int arow0 = (wm * 64 + fr) * 64;
  int brow0 = (wn * 64 + fr) * 64;

  f32x4 acc[4][4];
  #pragma unroll
  for (int m = 0; m < 4; ++m)
    #pragma unroll
    for (int n = 0; n < 4; ++n)
      acc[m][n] = (f32x4){0.f, 0.f, 0.f, 0.f};

  auto stage = [&](int kt, int b) {
    const u16* xs = xsrc + kt * 64;
    const u16* ys = ysrc + kt * 64;
    u16* la = &lds[b][0][sdst];
    u16* lb = &lds[b][1][sdst];
    #pragma unroll
    for (int i = 0; i < 4; ++i)
      gload_lds16(xs + (size_t)i * 8 * D, la + i * 512);
    #pragma unroll
    for (int i = 0; i < 4; ++i)
      gload_lds16(ys + (size_t)i * 8 * D, lb + i * 512);
  };

  int nkt = D >> 6;  // 8
  stage(0, 0);
  stage(1, 1);
  for (int t = 0; t < nkt; ++t) {
    int b = t & 1;
    // my 8 loads of tile t landed (8 of tile t+1 stay in flight)
    if (t + 1 < nkt)
      asm volatile("s_waitcnt vmcnt(8)" ::: "memory");
    else
      asm volatile("s_waitcnt vmcnt(0)" ::: "memory");
    __builtin_amdgcn_sched_barrier(0);
    __builtin_amdgcn_s_barrier();  // all waves' tile-t loads visible
    __builtin_amdgcn_sched_barrier(0);

    const u16* A = &lds[b][0][0];
    const u16* B = &lds[b][1][0];
    bf16x8 af[4][2], bf[4][2];
    #pragma unroll
    for (int m = 0; m < 4; ++m) {
      af[m][0] = *(const bf16x8*)&A[arow0 + m * 1024 + colx0];
      af[m][1] = *(const bf16x8*)&A[arow0 + m * 1024 + colx1];
    }
    #pragma unroll
    for (int n = 0; n < 4; ++n) {
      bf[n][0] = *(const bf16x8*)&B[brow0 + n * 1024 + colx0];
      bf[n][1] = *(const bf16x8*)&B[brow0 + n * 1024 + colx1];
    }

    // Swapped operands: D[j][i], j = fq*4 + r, i = fr.
    __builtin_amdgcn_s_setprio(1);
    #pragma unroll
    for (int m = 0; m < 4; ++m)
      #pragma unroll
      for (int n = 0; n < 4; ++n) {
        acc[m][n] = __builtin_amdgcn_mfma_f32_16x16x32_bf16(
            bf[n][0], af[m][0], acc[m][n], 0, 0, 0);
        acc[m][n] = __builtin_amdgcn_mfma_f32_16x16x32_bf16(
            bf[n][1], af[m][1], acc[m][n], 0, 0, 0);
      }
    __builtin_amdgcn_s_setprio(0);

    // my ds_reads of buf b done before anyone re-stages into it
    asm volatile("s_waitcnt lgkmcnt(0)" ::: "memory");
    __builtin_amdgcn_sched_barrier(0);
    __builtin_amdgcn_s_barrier();
    __builtin_amdgcn_sched_barrier(0);
    if (t + 2 < nkt) stage(t + 2, b);
  }

  // Epilogue: out = exp2(2*gl2*acc - gl2*|x|^2 - gl2*|y|^2), clamped <= 2^0.
  float gl2 = gptr[0] * 1.44269504088896f;  // gamma * log2(e)
  float m2gl2 = 2.0f * gl2;
  float4 gys[4];
  #pragma unroll
  for (int n = 0; n < 4; ++n) {
    float4 t4 = *reinterpret_cast<const float4*>(
        &ysq[bcol + wn * 64 + n * 16 + fq * 4]);
    gys[n].x = gl2 * t4.x;
    gys[n].y = gl2 * t4.y;
    gys[n].z = gl2 * t4.z;
    gys[n].w = gl2 * t4.w;
  }
  #pragma unroll
  for (int m = 0; m < 4; ++m) {
    int i = brow + wm * 64 + m * 16 + fr;
    float gxs = gl2 * xsq[i];
    size_t ro = (size_t)i * M;
    #pragma unroll
    for (int n = 0; n < 4; ++n) {
      int jb = bcol + wn * 64 + n * 16 + fq * 4;
      float4 e;
      e.x = exp2f(fminf(fmaf(m2gl2, acc[m][n][0], -(gxs + gys[n].x)), 0.f));
      e.y = exp2f(fminf(fmaf(m2gl2, acc[m][n][1], -(gxs + gys[n].y)), 0.f));
      e.z = exp2f(fminf(fmaf(m2gl2, acc[m][n][2], -(gxs + gys[n].z)), 0.f));
      e.w = exp2f(fminf(fmaf(m2gl2, acc[m][n][3], -(gxs + gys[n].w)), 0.f));
      *reinterpret_cast<float4*>(&out[ro + jb]) = e;
    }
  }
}

// ---------------------------------------------------------------------------
// Fallback: fp32 LDS-tiled, slow but correct for odd shapes.
// ---------------------------------------------------------------------------
__global__ __launch_bounds__(256) void rbf_naive(
    const float* __restrict__ x, const float* __restrict__ y,
    const float* __restrict__ gptr, float* __restrict__ out,
    int N, int M, int D) {
  __shared__ float xs[16][17];
  __shared__ float ys[16][17];
  int nbn = M / 16;
  int brow = (blockIdx.x / nbn) * 16;
  int bcol = (blockIdx.x % nbn) * 16;
  int ti = threadIdx.x >> 4, tj = threadIdx.x & 15;
  float dacc = 0.f, xacc = 0.f, yacc = 0.f;
  for (int k0 = 0; k0 < D; k0 += 16) {
    xs[ti][tj] = x[(size_t)(brow + ti) * D + k0 + tj];
    ys[ti][tj] = y[(size_t)(bcol + ti) * D + k0 + tj];
    __syncthreads();
    #pragma unroll
    for (int kk = 0; kk < 16; ++kk) {
      float xv = xs[ti][kk], yv = ys[tj][kk];
      dacc += xv * yv;
      xacc += xv * xv;
      yacc += yv * yv;
    }
    __syncthreads();
  }
  float gamma = gptr[0];
  float d2 = fmaxf(xacc + yacc - 2.f * dacc, 0.f);
  out[(size_t)(brow + ti) * M + (bcol + tj)] = __expf(-gamma * d2);
}

// ---------------------------------------------------------------------------
extern "C" void kernel_launch(void* const* d_in, const int* in_sizes, int n_in,
                              void* d_out, int out_size, void* d_ws,
                              size_t ws_size, hipStream_t stream) {
  const float* x = (const float*)d_in[0];
  const float* y = (const float*)d_in[1];
  const float* g = (const float*)d_in[2];
  float* out = (float*)d_out;

  const int D = 512;
  const int N = in_sizes[0] / D;
  const int M = in_sizes[1] / D;

  size_t need = (size_t)(N + M) * D * sizeof(u16) + (size_t)(N + M) * sizeof(float);
  bool shapes_ok = (N % BM == 0) && (M % BN == 0) && (D % BK == 0) && (D / BK >= 2);

  if (ws_size >= need && shapes_ok) {
    u16* xb = (u16*)d_ws;
    u16* yb = xb + (size_t)N * D;
    float* xsq = (float*)(yb + (size_t)M * D);
    float* ysq = xsq + N;

    rbf_prep<<<N + M, 128, 0, stream>>>(x, y, xb, yb, xsq, ysq, N, M, D);
    int nwg = (N / BM) * (M / BN);
    rbf_gemm<<<nwg, 256, 0, stream>>>(xb, yb, xsq, ysq, g, out, N, M, D);
  } else {
    rbf_naive<<<(N / 16) * (M / 16), 256, 0, stream>>>(x, y, g, out, N, M, D);
  }
}